// Round 1
// baseline (3242.425 us; speedup 1.0000x reference)
//
#include <hip/hip_runtime.h>
#include <hip/hip_bf16.h>

// Problem constants
constexpr int BB = 32;
constexpr int SS = 720;
constexpr int EE = 862;
constexpr int FF = 361;          // S/2+1
constexpr int M_ROWS = BB * EE;  // 27584 = 431*64
constexpr int NDFT = 724;        // 2*F padded to /4
constexpr int OUTSTRIDE = 4 * EE; // 3448
constexpr double PI2 = 6.283185307179586476925286766559;

// ---------------------------------------------------------------------------
// Kernel 0: build DFT matrix W[t][f] (cos / -sin) and full-period table ptab
// ---------------------------------------------------------------------------
__global__ __launch_bounds__(256) void build_trig_k(float* __restrict__ W,
                                                    float2* __restrict__ ptab) {
  int t = blockIdx.x;  // 0..719
  int tid = threadIdx.x;
  for (int f = tid; f < NDFT; f += 256) {
    double v = 0.0;
    if (f < FF) {
      int idx = (int)(((long long)f * t) % SS);
      v = cos(PI2 * idx / (double)SS);
    } else if (f < 2 * FF) {
      int ff = f - FF;
      int idx = (int)(((long long)ff * t) % SS);
      v = -sin(PI2 * idx / (double)SS);
    }
    W[(size_t)t * NDFT + f] = (float)v;
  }
  if (tid == 0) {
    double ang = PI2 * t / (double)SS;
    ptab[t] = make_float2((float)cos(ang), (float)sin(ang));
  }
}

// ---------------------------------------------------------------------------
// Transpose batch_x [B,S,E] -> xT [B*E, S]
// ---------------------------------------------------------------------------
__global__ __launch_bounds__(256) void transpose_in_k(const float* __restrict__ x,
                                                      float* __restrict__ xT) {
  __shared__ float tile[32][33];
  int b = blockIdx.z;
  int s0 = blockIdx.x * 32;
  int e0 = blockIdx.y * 32;
  int tx = threadIdx.x, ty = threadIdx.y;  // (32,8)
#pragma unroll
  for (int j = 0; j < 4; ++j) {
    int s = s0 + ty + j * 8;
    int e = e0 + tx;
    if (s < SS && e < EE) tile[ty + j * 8][tx] = x[((size_t)b * SS + s) * EE + e];
  }
  __syncthreads();
#pragma unroll
  for (int j = 0; j < 4; ++j) {
    int e = e0 + ty + j * 8;
    int s = s0 + tx;
    if (e < EE && s < SS) xT[((size_t)b * EE + e) * SS + s] = tile[tx][ty + j * 8];
  }
}

// ---------------------------------------------------------------------------
// Transpose normT [B*E, S] -> out[b,s,e] (col block 0)
// ---------------------------------------------------------------------------
__global__ __launch_bounds__(256) void transpose_norm_k(const float* __restrict__ normT,
                                                        float* __restrict__ out) {
  __shared__ float tile[32][33];
  int b = blockIdx.z;
  int e0 = blockIdx.x * 32;
  int s0 = blockIdx.y * 32;
  int tx = threadIdx.x, ty = threadIdx.y;
#pragma unroll
  for (int j = 0; j < 4; ++j) {
    int e = e0 + ty + j * 8;
    int s = s0 + tx;
    if (e < EE && s < SS) tile[ty + j * 8][tx] = normT[((size_t)b * EE + e) * SS + s];
  }
  __syncthreads();
#pragma unroll
  for (int j = 0; j < 4; ++j) {
    int s = s0 + ty + j * 8;
    int e = e0 + tx;
    if (s < SS && e < EE) out[((size_t)b * SS + s) * OUTSTRIDE + e] = tile[tx][ty + j * 8];
  }
}

// ---------------------------------------------------------------------------
// Tiled fp32 GEMM: C[M,N] = A[M,K] * W[K,N] (+bias)(+relu)
// A = [A1 (K1 cols) | A2 (K2 cols)] if CONCAT. M fixed = 27584, BM=BN=64, BK=16.
// OUTMODE 0: row-major Cout[M,N].  OUTMODE 1: Cout is d_out; C[row,n] ->
//            out[b, n, coloff + e] with row = b*EE+e (LDS-transposed stores).
// ---------------------------------------------------------------------------
template <bool RELU, bool CONCAT, int OUTMODE>
__global__ __launch_bounds__(256) void gemm_k(const float* __restrict__ A1, int K1,
                                              const float* __restrict__ A2, int K2,
                                              const float* __restrict__ W,
                                              const float* __restrict__ bias,
                                              float* __restrict__ Cout, int N,
                                              int coloff) {
  const int K = CONCAT ? (K1 + K2) : K1;
  __shared__ float As[16][68];  // transposed A tile [k][row], padded
  __shared__ float Bs[16][68];  // [k][n], padded
  int tid = threadIdx.x;
  int row0 = blockIdx.x * 64;
  int n0 = blockIdx.y * 64;
  int tx = tid & 15, ty = tid >> 4;
  int lr = tid >> 2;            // A: row in tile
  int lkc = (tid & 3) * 4;      // A: k offset in tile (0,4,8,12)
  int bkk = tid >> 4;           // B: k row
  int bn = (tid & 15) * 4;      // B: n offset

  float acc[4][4] = {};

  for (int k0 = 0; k0 < K; k0 += 16) {
    int ka = k0 + lkc;
    float4 av;
    if (!CONCAT || ka < K1) {
      av = *(const float4*)(A1 + (size_t)(row0 + lr) * K1 + ka);
    } else {
      av = *(const float4*)(A2 + (size_t)(row0 + lr) * K2 + (ka - K1));
    }
    float4 bv = make_float4(0.f, 0.f, 0.f, 0.f);
    if (n0 + bn < N) bv = *(const float4*)(W + (size_t)(k0 + bkk) * N + n0 + bn);
    __syncthreads();
    As[lkc + 0][lr] = av.x;
    As[lkc + 1][lr] = av.y;
    As[lkc + 2][lr] = av.z;
    As[lkc + 3][lr] = av.w;
    *(float4*)&Bs[bkk][bn] = bv;
    __syncthreads();
#pragma unroll
    for (int kk = 0; kk < 16; ++kk) {
      float a4[4], b4[4];
      *(float4*)a4 = *(const float4*)&As[kk][ty * 4];
      *(float4*)b4 = *(const float4*)&Bs[kk][tx * 4];
#pragma unroll
      for (int i = 0; i < 4; ++i)
#pragma unroll
        for (int j = 0; j < 4; ++j) acc[i][j] = fmaf(a4[i], b4[j], acc[i][j]);
    }
  }

  if constexpr (OUTMODE == 0) {
    int n = n0 + tx * 4;
    if (n < N) {
#pragma unroll
      for (int i = 0; i < 4; ++i) {
        float v[4];
#pragma unroll
        for (int j = 0; j < 4; ++j) {
          float t = acc[i][j];
          if (bias) t += bias[n + j];
          if (RELU) t = fmaxf(t, 0.f);
          v[j] = t;
        }
        *(float4*)(Cout + (size_t)(row0 + ty * 4 + i) * N + n) = *(float4*)v;
      }
    }
  } else {
    __shared__ float Ct[64 * 65];
#pragma unroll
    for (int i = 0; i < 4; ++i)
#pragma unroll
      for (int j = 0; j < 4; ++j) {
        int n = n0 + tx * 4 + j;
        float t = acc[i][j] + ((n < N) ? bias[n] : 0.f);
        Ct[(ty * 4 + i) * 65 + tx * 4 + j] = t;
      }
    __syncthreads();
#pragma unroll
    for (int jj = 0; jj < 16; ++jj) {
      int idx = jj * 256 + tid;
      int e_l = idx & 63, n_l = idx >> 6;
      int n = n0 + n_l;
      if (n < N) {
        int row = row0 + e_l;
        int b = row / EE, e = row - b * EE;
        Cout[((size_t)b * SS + n) * OUTSTRIDE + coloff + e] = Ct[e_l * 65 + n_l];
      }
    }
  }
}

// ---------------------------------------------------------------------------
// Per-row: top-20 of |X|^2, synthesize x_filtered, window mean/std, norm.
// ---------------------------------------------------------------------------
__global__ __launch_bounds__(256) void synth_stats_k(
    const float* __restrict__ dft,   // [M][724]: re[0..360], im[361..721]
    const float* __restrict__ xT,    // [M][720]
    const float2* __restrict__ ptab, // [720] (cos, sin)
    float* __restrict__ xfT, float* __restrict__ meanT, float* __restrict__ stdT,
    float* __restrict__ normT,       // may be null -> scattered writes to out
    float* __restrict__ out) {
  __shared__ float xrow[SS];
  __shared__ float nrow[SS];
  __shared__ float re[FF], im[FF], mag[FF];
  __shared__ float2 tab[SS];
  __shared__ float cre[20], cim[20];
  __shared__ int sel[20];
  __shared__ float wbv[4];
  __shared__ int wbi[4];

  int row = blockIdx.x;
  int tid = threadIdx.x;
  const float* dr = dft + (size_t)row * NDFT;

  for (int i = tid; i < SS; i += 256) {
    xrow[i] = xT[(size_t)row * SS + i];
    tab[i] = ptab[i];
  }
  for (int f = tid; f < FF; f += 256) {
    float r = dr[f], iv = dr[FF + f];
    re[f] = r;
    im[f] = iv;
    mag[f] = r * r + iv * iv;
  }
  __syncthreads();

  // top-20 (strict > with ascending scan == lowest-index tie-break, like lax.top_k)
  for (int k = 0; k < 20; ++k) {
    float bv = -1.f;
    int bi = 1 << 20;
    for (int f = tid; f < FF; f += 256) {
      float m = mag[f];
      if (m > bv) { bv = m; bi = f; }
    }
#pragma unroll
    for (int off = 32; off; off >>= 1) {
      float ov = __shfl_down(bv, off);
      int oi = __shfl_down(bi, off);
      if (ov > bv || (ov == bv && oi < bi)) { bv = ov; bi = oi; }
    }
    if ((tid & 63) == 0) { wbv[tid >> 6] = bv; wbi[tid >> 6] = bi; }
    __syncthreads();
    if (tid == 0) {
      float fv = wbv[0]; int fi = wbi[0];
#pragma unroll
      for (int w = 1; w < 4; ++w) {
        if (wbv[w] > fv || (wbv[w] == fv && wbi[w] < fi)) { fv = wbv[w]; fi = wbi[w]; }
      }
      sel[k] = fi;
      mag[fi] = -1.f;
      float coef = (fi == 0 || fi == SS / 2) ? 1.f : 2.f;
      cre[k] = coef * re[fi] * (1.f / SS);
      cim[k] = coef * im[fi] * (1.f / SS);
    }
    __syncthreads();
  }

  // synthesize x_filtered row; nrow = x - xf
  for (int t = tid; t < SS; t += 256) {
    float a = 0.f;
#pragma unroll
    for (int k = 0; k < 20; ++k) {
      int f = sel[k];
      int idx = (f * t) % SS;
      float2 cs = tab[idx];
      a = fmaf(cre[k], cs.x, a);
      a = fmaf(-cim[k], cs.y, a);
    }
    xfT[(size_t)row * SS + t] = a;
    nrow[t] = xrow[t] - a;
  }
  __syncthreads();

  // sliding window stats (w=24, replicate pad)
  for (int t = tid; t < SS; t += 256) {
    float s1 = 0.f, s2 = 0.f;
#pragma unroll
    for (int j = -12; j < 12; ++j) {
      int u = t + j;
      u = u < 0 ? 0 : (u > SS - 1 ? SS - 1 : u);
      float v = nrow[u];
      s1 += v;
      s2 = fmaf(v, v, s2);
    }
    float mean = s1 * (1.f / 24.f);
    float var = fmaxf(s2 * (1.f / 24.f) - mean * mean, 0.f);
    float sd = sqrtf(var + 1e-5f);
    meanT[(size_t)row * SS + t] = mean;
    stdT[(size_t)row * SS + t] = sd;
    float nv = (nrow[t] - mean) / sd;
    if (normT) {
      normT[(size_t)row * SS + t] = nv;
    } else {
      int b = row / EE, e = row - b * EE;
      out[((size_t)b * SS + t) * OUTSTRIDE + e] = nv;
    }
  }
}

// ---------------------------------------------------------------------------
extern "C" void kernel_launch(void* const* d_in, const int* in_sizes, int n_in,
                              void* d_out, int out_size, void* d_ws, size_t ws_size,
                              hipStream_t stream) {
  const float* x = (const float*)d_in[0];
  const float* Wf1 = (const float*)d_in[1];
  const float* bf1 = (const float*)d_in[2];
  const float* Wf2 = (const float*)d_in[3];
  const float* bf2 = (const float*)d_in[4];
  const float* Wf3 = (const float*)d_in[5];
  const float* bf3 = (const float*)d_in[6];
  const float* Wp1 = (const float*)d_in[7];
  const float* bp1 = (const float*)d_in[8];
  const float* Wp2 = (const float*)d_in[9];
  const float* bp2 = (const float*)d_in[10];
  const float* Wp3 = (const float*)d_in[11];
  const float* bp3 = (const float*)d_in[12];
  float* out = (float*)d_out;
  float* ws = (float*)d_ws;

  const size_t MR = (size_t)M_ROWS;
  size_t o = 0;
  float* xT = ws + o;    o += MR * SS;
  float* xfT = ws + o;   o += MR * SS;
  float* meanT = ws + o; o += MR * SS;
  float* stdT = ws + o;  o += MR * SS;
  float* trig = ws + o;  o += (size_t)SS * NDFT;
  float* ptab = ws + o;  o += 2 * SS;
  // region shared by dft (phase 1) and hbuf/h2buf (phase 2)
  float* dft = ws + o;
  float* hbuf = ws + o;
  float* h2buf = ws + o + MR * 256;
  size_t region = MR * 256 + MR * 512;  // 21.2M floats >= dft's 19.97M
  o += region;
  float* normT = nullptr;
  if (ws_size >= (o + MR * SS) * sizeof(float)) normT = ws + o;

  dim3 tb(32, 8);

  build_trig_k<<<SS, 256, 0, stream>>>(trig, (float2*)ptab);
  transpose_in_k<<<dim3((SS + 31) / 32, (EE + 31) / 32, BB), tb, 0, stream>>>(x, xT);

  // forward DFT as GEMM -> dft [M,724]
  gemm_k<false, false, 0><<<dim3(431, 12), 256, 0, stream>>>(
      xT, SS, nullptr, 0, trig, nullptr, dft, NDFT, 0);

  synth_stats_k<<<M_ROWS, 256, 0, stream>>>(dft, xT, (const float2*)ptab, xfT, meanT,
                                            stdT, normT, out);

  // freq chain
  gemm_k<true, false, 0><<<dim3(431, 1), 256, 0, stream>>>(
      xfT, SS, nullptr, 0, Wf1, bf1, hbuf, 64, 0);
  gemm_k<true, true, 0><<<dim3(431, 2), 256, 0, stream>>>(
      hbuf, 64, xT, SS, Wf2, bf2, h2buf, 128, 0);
  gemm_k<false, false, 1><<<dim3(431, 12), 256, 0, stream>>>(
      h2buf, 128, nullptr, 0, Wf3, bf3, out, SS, EE);

  // mean chain
  gemm_k<true, false, 0><<<dim3(431, 4), 256, 0, stream>>>(
      meanT, SS, nullptr, 0, Wp1, bp1, hbuf, 256, 0);
  gemm_k<true, true, 0><<<dim3(431, 8), 256, 0, stream>>>(
      hbuf, 256, xT, SS, Wp2, bp2, h2buf, 512, 0);
  gemm_k<false, false, 1><<<dim3(431, 12), 256, 0, stream>>>(
      h2buf, 512, nullptr, 0, Wp3, bp3, out, SS, 2 * EE);

  // std chain
  gemm_k<true, false, 0><<<dim3(431, 4), 256, 0, stream>>>(
      stdT, SS, nullptr, 0, Wp1, bp1, hbuf, 256, 0);
  gemm_k<true, true, 0><<<dim3(431, 8), 256, 0, stream>>>(
      hbuf, 256, xT, SS, Wp2, bp2, h2buf, 512, 0);
  gemm_k<false, false, 1><<<dim3(431, 12), 256, 0, stream>>>(
      h2buf, 512, nullptr, 0, Wp3, bp3, out, SS, 3 * EE);

  if (normT) {
    transpose_norm_k<<<dim3((EE + 31) / 32, (SS + 31) / 32, BB), tb, 0, stream>>>(
        normT, out);
  }
}

// Round 2
// 2136.681 us; speedup vs baseline: 1.5175x; 1.5175x over previous
//
#include <hip/hip_runtime.h>

using short8 = __attribute__((ext_vector_type(8))) short;
using f32x4v = __attribute__((ext_vector_type(4))) float;

constexpr int SS = 720;
constexpr int EE = 862;
constexpr int FF = 361;          // S/2+1
constexpr int MR = 27584;        // 32*862 = 431*64 = 215.5*128
constexpr int NDFT = 724;        // 2*F padded to /4
constexpr int OUTSTRIDE = 4 * EE;
constexpr double PI2 = 6.283185307179586476925286766559;

__device__ __forceinline__ unsigned short f2bf(float v) {
  unsigned u = __float_as_uint(v);
  u += 0x7fff + ((u >> 16) & 1);  // RNE
  return (unsigned short)(u >> 16);
}
__device__ __forceinline__ float bf2f(unsigned short h) {
  return __uint_as_float(((unsigned)h) << 16);
}

// ---------------------------------------------------------------------------
// trig tables: W[t][f] = cos / -sin DFT matrix (720x724), ptab[t] = (cos,sin)
// ---------------------------------------------------------------------------
__global__ __launch_bounds__(256) void build_trig_k(float* __restrict__ W,
                                                    float2* __restrict__ ptab) {
  int t = blockIdx.x;
  int tid = threadIdx.x;
  for (int f = tid; f < NDFT; f += 256) {
    double v = 0.0;
    if (f < FF) {
      int idx = (int)(((long long)f * t) % SS);
      v = cos(PI2 * idx / (double)SS);
    } else if (f < 2 * FF) {
      int ff = f - FF;
      int idx = (int)(((long long)ff * t) % SS);
      v = -sin(PI2 * idx / (double)SS);
    }
    W[(size_t)t * NDFT + f] = (float)v;
  }
  if (tid == 0) {
    double ang = PI2 * t / (double)SS;
    ptab[t] = make_float2((float)cos(ang), (float)sin(ang));
  }
}

// ---------------------------------------------------------------------------
// Transpose batch_x [B,S,E] -> xT [B*E, S]
// ---------------------------------------------------------------------------
__global__ __launch_bounds__(256) void transpose_in_k(const float* __restrict__ x,
                                                      float* __restrict__ xT) {
  __shared__ float tile[32][33];
  int b = blockIdx.z;
  int s0 = blockIdx.x * 32;
  int e0 = blockIdx.y * 32;
  int tx = threadIdx.x, ty = threadIdx.y;
#pragma unroll
  for (int j = 0; j < 4; ++j) {
    int s = s0 + ty + j * 8;
    int e = e0 + tx;
    if (s < SS && e < EE) tile[ty + j * 8][tx] = x[((size_t)b * SS + s) * EE + e];
  }
  __syncthreads();
#pragma unroll
  for (int j = 0; j < 4; ++j) {
    int e = e0 + ty + j * 8;
    int s = s0 + tx;
    if (e < EE && s < SS) xT[((size_t)b * EE + e) * SS + s] = tile[tx][ty + j * 8];
  }
}

// ---------------------------------------------------------------------------
// Transpose normT [B*E, S] -> out[b,s,e] col block 0
// ---------------------------------------------------------------------------
__global__ __launch_bounds__(256) void transpose_norm_k(const float* __restrict__ normT,
                                                        float* __restrict__ out) {
  __shared__ float tile[32][33];
  int b = blockIdx.z;
  int e0 = blockIdx.x * 32;
  int s0 = blockIdx.y * 32;
  int tx = threadIdx.x, ty = threadIdx.y;
#pragma unroll
  for (int j = 0; j < 4; ++j) {
    int e = e0 + ty + j * 8;
    int s = s0 + tx;
    if (e < EE && s < SS) tile[ty + j * 8][tx] = normT[((size_t)b * EE + e) * SS + s];
  }
  __syncthreads();
#pragma unroll
  for (int j = 0; j < 4; ++j) {
    int s = s0 + ty + j * 8;
    int e = e0 + tx;
    if (s < SS && e < EE) out[((size_t)b * SS + s) * OUTSTRIDE + e] = tile[tx][ty + j * 8];
  }
}

// ---------------------------------------------------------------------------
// fp32 GEMM for the DFT only (precision-critical for top-k selection).
// C[M,724] = xT[M,720] * trig[720,724]. 64x64 tile, 4x4 microtile (round-1).
// ---------------------------------------------------------------------------
__global__ __launch_bounds__(256) void dft_gemm_k(const float* __restrict__ A,
                                                  const float* __restrict__ W,
                                                  float* __restrict__ C) {
  __shared__ float As[16][68];
  __shared__ float Bs[16][68];
  int tid = threadIdx.x;
  int row0 = blockIdx.x * 64;
  int n0 = blockIdx.y * 64;
  int tx = tid & 15, ty = tid >> 4;
  int lr = tid >> 2;
  int lkc = (tid & 3) * 4;
  int bkk = tid >> 4;
  int bn = (tid & 15) * 4;
  float acc[4][4] = {};
  for (int k0 = 0; k0 < SS; k0 += 16) {
    float4 av = *(const float4*)(A + (size_t)(row0 + lr) * SS + k0 + lkc);
    float4 bv = make_float4(0.f, 0.f, 0.f, 0.f);
    if (n0 + bn < NDFT) bv = *(const float4*)(W + (size_t)(k0 + bkk) * NDFT + n0 + bn);
    __syncthreads();
    As[lkc + 0][lr] = av.x;
    As[lkc + 1][lr] = av.y;
    As[lkc + 2][lr] = av.z;
    As[lkc + 3][lr] = av.w;
    *(float4*)&Bs[bkk][bn] = bv;
    __syncthreads();
#pragma unroll
    for (int kk = 0; kk < 16; ++kk) {
      float a4[4], b4[4];
      *(float4*)a4 = *(const float4*)&As[kk][ty * 4];
      *(float4*)b4 = *(const float4*)&Bs[kk][tx * 4];
#pragma unroll
      for (int i = 0; i < 4; ++i)
#pragma unroll
        for (int j = 0; j < 4; ++j) acc[i][j] = fmaf(a4[i], b4[j], acc[i][j]);
    }
  }
  int n = n0 + tx * 4;
  if (n < NDFT) {
#pragma unroll
    for (int i = 0; i < 4; ++i) {
      float v[4];
#pragma unroll
      for (int j = 0; j < 4; ++j) v[j] = acc[i][j];
      *(float4*)(C + (size_t)(row0 + ty * 4 + i) * NDFT + n) = *(float4*)v;
    }
  }
}

// ---------------------------------------------------------------------------
// Weight convert: W[K,N] fp32 -> WT hi/lo bf16 [Npad, Kp] (zero-padded)
// ---------------------------------------------------------------------------
__global__ __launch_bounds__(256) void conv_w_k(const float* __restrict__ W, int K, int N,
                                                int Kp, unsigned short* __restrict__ WTh,
                                                unsigned short* __restrict__ WTl) {
  int n = blockIdx.x;  // 0..Npad-1
  for (int k = threadIdx.x; k < Kp; k += 256) {
    float v = (n < N && k < K) ? W[(size_t)k * N + n] : 0.f;
    unsigned short h = f2bf(v);
    WTh[(size_t)n * Kp + k] = h;
    WTl[(size_t)n * Kp + k] = f2bf(v - bf2f(h));
  }
}

// ---------------------------------------------------------------------------
// bf16x3 MFMA GEMM. C[M,N] = A[M,K] * W[K,N] (+bias)(+relu)
// A fp32 (reg-staged, split to bf16 hi/lo into swizzled LDS; masked -> zeros).
// A = [A1 (K1 cols) | A2 (K2 cols, stride 720)] ; tiles of 64 k; BM=128 BN=64.
// B = pre-split WT hi/lo [Npad][Kp].
// OUTMODE 0: fp32 row-major [M][ldc]. OUTMODE 1: transposed scatter into d_out.
// ---------------------------------------------------------------------------
template <int OUTMODE, bool RELU>
__global__ __launch_bounds__(256, 2) void mfma_gemm_k(
    const float* __restrict__ A1, int sA1, int K1,
    const float* __restrict__ A2, int K2, int ktiles,
    const unsigned short* __restrict__ WTh, const unsigned short* __restrict__ WTl,
    int Kp, const float* __restrict__ bias, int N,
    float* __restrict__ Cout, int ldc, int coloff) {
  // LDS: Ah [128][64] @0, Al @8192, Bh [64][64] @16384, Bl @20480 (shorts)
  __shared__ __align__(16) short smem[24576];
  const int tid = threadIdx.x;
  const int wid = tid >> 6, l = tid & 63;
  const int row0 = blockIdx.x * 128;
  const int n0 = blockIdx.y * 64;
  const int lg = l >> 4, lm = l & 15;

  f32x4v acc[2][4];
  const f32x4v zero4 = {0.f, 0.f, 0.f, 0.f};
#pragma unroll
  for (int i = 0; i < 2; ++i)
#pragma unroll
    for (int j = 0; j < 4; ++j) acc[i][j] = zero4;

  for (int kt = 0; kt < ktiles; ++kt) {
    const int k0 = kt * 64;
    const float* src;
    int str, soff, lim;
    if (k0 < K1) { src = A1; str = sA1; soff = k0; lim = K1; }
    else         { src = A2; str = SS;  soff = k0 - K1; lim = K2; }
    __syncthreads();
    // ---- stage A: fp32 -> hi/lo bf16, XOR-swizzled granules ----
#pragma unroll
    for (int p = 0; p < 4; ++p) {
      int gid = p * 256 + tid;  // 1024 granules (128 rows x 8)
      int rw = gid >> 3, c8 = gid & 7;
      int rowg = row0 + rw;
      if (rowg > MR - 1) rowg = MR - 1;
      int col0 = soff + c8 * 8;
      float4 va = make_float4(0.f, 0.f, 0.f, 0.f), vb = va;
      if (col0 < lim) {
        const float* ap = src + (size_t)rowg * str + col0;
        va = *(const float4*)ap;
        vb = *(const float4*)(ap + 4);
      }
      float vv[8] = {va.x, va.y, va.z, va.w, vb.x, vb.y, vb.z, vb.w};
      short8 hi, lo;
#pragma unroll
      for (int q = 0; q < 8; ++q) {
        unsigned short h = f2bf(vv[q]);
        hi[q] = (short)h;
        lo[q] = (short)f2bf(vv[q] - bf2f(h));
      }
      int slot = rw * 64 + ((c8 ^ (rw & 7)) << 3);
      *(short8*)&smem[slot] = hi;
      *(short8*)&smem[8192 + slot] = lo;
    }
    // ---- stage B (pre-split weights) ----
#pragma unroll
    for (int p = 0; p < 2; ++p) {
      int gid = p * 256 + tid;  // 512 granules (64 rows x 8)
      int rw = gid >> 3, c8 = gid & 7;
      size_t goff = (size_t)(n0 + rw) * Kp + k0 + c8 * 8;
      short8 vh = *(const short8*)(WTh + goff);
      short8 vl = *(const short8*)(WTl + goff);
      int slot = rw * 64 + ((c8 ^ (rw & 7)) << 3);
      *(short8*)&smem[16384 + slot] = vh;
      *(short8*)&smem[20480 + slot] = vl;
    }
    __syncthreads();
    // ---- compute: wave owns rows [wid*32, wid*32+32) x all 64 cols ----
#pragma unroll
    for (int ks = 0; ks < 2; ++ks) {
      short8 ah[2], al[2], bh[4], bl[4];
#pragma unroll
      for (int fi = 0; fi < 2; ++fi) {
        int r = wid * 32 + fi * 16 + lm;
        int slot = r * 64 + (((4 * ks + lg) ^ (r & 7)) << 3);
        ah[fi] = *(const short8*)&smem[slot];
        al[fi] = *(const short8*)&smem[8192 + slot];
      }
#pragma unroll
      for (int fj = 0; fj < 4; ++fj) {
        int r = fj * 16 + lm;
        int slot = r * 64 + (((4 * ks + lg) ^ (r & 7)) << 3);
        bh[fj] = *(const short8*)&smem[16384 + slot];
        bl[fj] = *(const short8*)&smem[20480 + slot];
      }
#pragma unroll
      for (int fi = 0; fi < 2; ++fi)
#pragma unroll
        for (int fj = 0; fj < 4; ++fj) {
          acc[fi][fj] = __builtin_amdgcn_mfma_f32_16x16x32_bf16(ah[fi], bh[fj], acc[fi][fj], 0, 0, 0);
          acc[fi][fj] = __builtin_amdgcn_mfma_f32_16x16x32_bf16(ah[fi], bl[fj], acc[fi][fj], 0, 0, 0);
          acc[fi][fj] = __builtin_amdgcn_mfma_f32_16x16x32_bf16(al[fi], bh[fj], acc[fi][fj], 0, 0, 0);
        }
    }
  }

  if constexpr (OUTMODE == 0) {
#pragma unroll
    for (int fi = 0; fi < 2; ++fi)
#pragma unroll
      for (int fj = 0; fj < 4; ++fj) {
        int col = n0 + fj * 16 + lm;
        float bval = bias[col];
#pragma unroll
        for (int q = 0; q < 4; ++q) {
          int row = row0 + wid * 32 + fi * 16 + lg * 4 + q;
          if (row < MR) {
            float v = acc[fi][fj][q] + bval;
            if (RELU) v = fmaxf(v, 0.f);
            Cout[(size_t)row * ldc + col] = v;
          }
        }
      }
  } else {
    __syncthreads();
    float* Ct = (float*)smem;  // [64 cols][132] (rows padded)
#pragma unroll
    for (int fi = 0; fi < 2; ++fi)
#pragma unroll
      for (int fj = 0; fj < 4; ++fj) {
        int cl = fj * 16 + lm;
        int coln = n0 + cl;
        float bval = (coln < N) ? bias[coln] : 0.f;
#pragma unroll
        for (int q = 0; q < 4; ++q) {
          int rl = wid * 32 + fi * 16 + lg * 4 + q;
          Ct[cl * 132 + rl] = acc[fi][fj][q] + bval;
        }
      }
    __syncthreads();
#pragma unroll
    for (int it = 0; it < 32; ++it) {
      int idx = it * 256 + tid;
      int e_l = idx & 127, n_l = idx >> 7;
      int row = row0 + e_l, n = n0 + n_l;
      if (row < MR && n < N) {
        int b = row / EE, e = row - b * EE;
        Cout[((size_t)b * SS + n) * OUTSTRIDE + coloff + e] = Ct[n_l * 132 + e_l];
      }
    }
  }
}

// ---------------------------------------------------------------------------
// Wave-per-row: top-20 of |X|^2 (shuffle argmax, lowest-index tie-break),
// synthesize x_filtered by rotation recurrence, sliding window mean/std, norm.
// ---------------------------------------------------------------------------
__global__ __launch_bounds__(256) void synth_stats_k(
    const float* __restrict__ dft, const float* __restrict__ xT,
    const float2* __restrict__ ptab, float* __restrict__ xfT,
    float* __restrict__ meanT, float* __restrict__ stdT, float* __restrict__ normT) {
  __shared__ float cosT[SS], sinT[SS];
  __shared__ float nrowS[4][SS];
  __shared__ int selS[4][20];
  __shared__ float creS[4][20], cimS[4][20];

  const int tid = threadIdx.x;
  const int wid = tid >> 6, l = tid & 63;
  const int row = blockIdx.x * 4 + wid;

  for (int i = tid; i < SS; i += 256) {
    float2 p = ptab[i];
    cosT[i] = p.x;
    sinT[i] = p.y;
  }

  const float* dr = dft + (size_t)row * NDFT;
  float re[6], im[6], mg[6];
#pragma unroll
  for (int s = 0; s < 6; ++s) {
    int f = l + 64 * s;
    if (f < FF) {
      re[s] = dr[f];
      im[s] = dr[FF + f];
      mg[s] = re[s] * re[s] + im[s] * im[s];
    } else {
      re[s] = 0.f; im[s] = 0.f; mg[s] = -1e30f;
    }
  }
  __syncthreads();  // trig tables ready

  // ---- top-20 ----
  for (int k = 0; k < 20; ++k) {
    float bv = -1e29f;
    int bi = 1 << 30;
#pragma unroll
    for (int s = 0; s < 6; ++s) {
      int f = l + 64 * s;
      if (mg[s] > bv) { bv = mg[s]; bi = f; }
    }
#pragma unroll
    for (int off = 32; off >= 1; off >>= 1) {
      float ov = __shfl_xor(bv, off);
      int oi = __shfl_xor(bi, off);
      if (ov > bv || (ov == bv && oi < bi)) { bv = ov; bi = oi; }
    }
    float rw = 0.f, iw = 0.f;
    int lw = bi & 63;
    if (lw == l) {
      int sw = bi >> 6;
#pragma unroll
      for (int s = 0; s < 6; ++s)
        if (s == sw) { rw = re[s]; iw = im[s]; mg[s] = -2e30f; }
    }
    rw = __shfl(rw, lw);
    iw = __shfl(iw, lw);
    if (l == 0) {
      float cf = (bi == 0 || bi == 360) ? (1.f / 720.f) : (2.f / 720.f);
      selS[wid][k] = bi;
      creS[wid][k] = cf * rw;
      cimS[wid][k] = cf * iw;
    }
  }
  __syncthreads();

  // ---- synthesize xf for lane's 12 contiguous t (t0 = 12*l) ----
  const int t0 = 12 * l;
  float xfv[12];
#pragma unroll
  for (int j = 0; j < 12; ++j) xfv[j] = 0.f;
  for (int k = 0; k < 20; ++k) {
    int f = selS[wid][k];
    float cre = creS[wid][k], cim = cimS[wid][k];
    int i0 = (f * t0) % SS;
    float c = cosT[i0], s = sinT[i0];
    float cr = cosT[f], sr = sinT[f];  // rotation by one t-step
#pragma unroll
    for (int j = 0; j < 12; ++j) {
      xfv[j] = fmaf(cre, c, xfv[j]);
      xfv[j] = fmaf(-cim, s, xfv[j]);
      float cn = c * cr - s * sr;
      s = s * cr + c * sr;
      c = cn;
    }
  }

  float nr[12];
  if (l < 60) {
    const float* xr = xT + (size_t)row * SS + t0;
    float4 x0 = *(const float4*)(xr);
    float4 x1 = *(const float4*)(xr + 4);
    float4 x2 = *(const float4*)(xr + 8);
    float xv[12] = {x0.x, x0.y, x0.z, x0.w, x1.x, x1.y, x1.z, x1.w, x2.x, x2.y, x2.z, x2.w};
#pragma unroll
    for (int j = 0; j < 12; ++j) nr[j] = xv[j] - xfv[j];
    float* xfp = xfT + (size_t)row * SS + t0;
    *(float4*)(xfp + 0) = make_float4(xfv[0], xfv[1], xfv[2], xfv[3]);
    *(float4*)(xfp + 4) = make_float4(xfv[4], xfv[5], xfv[6], xfv[7]);
    *(float4*)(xfp + 8) = make_float4(xfv[8], xfv[9], xfv[10], xfv[11]);
    float* np = &nrowS[wid][t0];
    *(float4*)(np + 0) = make_float4(nr[0], nr[1], nr[2], nr[3]);
    *(float4*)(np + 4) = make_float4(nr[4], nr[5], nr[6], nr[7]);
    *(float4*)(np + 8) = make_float4(nr[8], nr[9], nr[10], nr[11]);
  }
  __syncthreads();

  // ---- sliding-window stats (w=24, replicate pad) + norm ----
  if (l < 60) {
    float s1 = 0.f, s2 = 0.f;
#pragma unroll
    for (int d = -12; d < 12; ++d) {
      int u = t0 + d;
      u = u < 0 ? 0 : u;
      float v = nrowS[wid][u];
      s1 += v;
      s2 = fmaf(v, v, s2);
    }
    float mv[12], sv[12], nv[12];
#pragma unroll
    for (int j = 0; j < 12; ++j) {
      int t = t0 + j;
      float mean = s1 * (1.f / 24.f);
      float var = fmaxf(s2 * (1.f / 24.f) - mean * mean, 0.f);
      float sd = sqrtf(var + 1e-5f);
      mv[j] = mean;
      sv[j] = sd;
      nv[j] = (nr[j] - mean) / sd;
      int ua = t + 12; if (ua > SS - 1) ua = SS - 1;
      int ur = t - 12; if (ur < 0) ur = 0;
      float va = nrowS[wid][ua], vr = nrowS[wid][ur];
      s1 += va - vr;
      s2 += va * va - vr * vr;
    }
    float* mp = meanT + (size_t)row * SS + t0;
    float* sp = stdT + (size_t)row * SS + t0;
    float* op = normT + (size_t)row * SS + t0;
    *(float4*)(mp + 0) = make_float4(mv[0], mv[1], mv[2], mv[3]);
    *(float4*)(mp + 4) = make_float4(mv[4], mv[5], mv[6], mv[7]);
    *(float4*)(mp + 8) = make_float4(mv[8], mv[9], mv[10], mv[11]);
    *(float4*)(sp + 0) = make_float4(sv[0], sv[1], sv[2], sv[3]);
    *(float4*)(sp + 4) = make_float4(sv[4], sv[5], sv[6], sv[7]);
    *(float4*)(sp + 8) = make_float4(sv[8], sv[9], sv[10], sv[11]);
    *(float4*)(op + 0) = make_float4(nv[0], nv[1], nv[2], nv[3]);
    *(float4*)(op + 4) = make_float4(nv[4], nv[5], nv[6], nv[7]);
    *(float4*)(op + 8) = make_float4(nv[8], nv[9], nv[10], nv[11]);
  }
}

// ---------------------------------------------------------------------------
extern "C" void kernel_launch(void* const* d_in, const int* in_sizes, int n_in,
                              void* d_out, int out_size, void* d_ws, size_t ws_size,
                              hipStream_t stream) {
  const float* x = (const float*)d_in[0];
  const float* Wf1 = (const float*)d_in[1];
  const float* bf1 = (const float*)d_in[2];
  const float* Wf2 = (const float*)d_in[3];
  const float* bf2 = (const float*)d_in[4];
  const float* Wf3 = (const float*)d_in[5];
  const float* bf3 = (const float*)d_in[6];
  const float* Wp1 = (const float*)d_in[7];
  const float* bp1 = (const float*)d_in[8];
  const float* Wp2 = (const float*)d_in[9];
  const float* bp2 = (const float*)d_in[10];
  const float* Wp3 = (const float*)d_in[11];
  const float* bp3 = (const float*)d_in[12];
  float* out = (float*)d_out;
  float* ws = (float*)d_ws;

  constexpr size_t SZ_MT = (size_t)MR * SS;  // 19,860,480 floats
  float* xT = ws;
  float* xfT = xT + SZ_MT;
  float* meanT = xfT + SZ_MT;
  float* stdT = meanT + SZ_MT;
  float* trig = stdT + SZ_MT;                       // 720*724
  float* ptab = trig + (size_t)SS * NDFT;           // 1440
  float* region = ptab + 1440;                      // MR*768 floats
  float* dftb = region;                             // phase 1
  float* h1 = region;                               // phase f
  float* h2 = region + (size_t)MR * 64;
  float* hp = region;                               // phase p
  float* hp2 = region + (size_t)MR * 256;
  float* normT = region + (size_t)MR * 768;         // MR*720 floats
  // weights overlay normT after transpose_norm consumes it
  unsigned short* wts = (unsigned short*)normT;
  unsigned short* wf1h = wts;
  unsigned short* wf1l = wf1h + 64 * 768;
  unsigned short* wf2h = wf1l + 64 * 768;
  unsigned short* wf2l = wf2h + 128 * 832;
  unsigned short* wf3h = wf2l + 128 * 832;
  unsigned short* wf3l = wf3h + 768 * 128;
  unsigned short* wp1h = wf3l + 768 * 128;
  unsigned short* wp1l = wp1h + 256 * 768;
  unsigned short* wp2h = wp1l + 256 * 768;
  unsigned short* wp2l = wp2h + 512 * 1024;
  unsigned short* wp3h = wp2l + 512 * 1024;
  unsigned short* wp3l = wp3h + 768 * 512;

  dim3 tb(32, 8);

  build_trig_k<<<SS, 256, 0, stream>>>(trig, (float2*)ptab);
  transpose_in_k<<<dim3(23, 27, 32), tb, 0, stream>>>(x, xT);
  dft_gemm_k<<<dim3(431, 12), 256, 0, stream>>>(xT, trig, dftb);
  synth_stats_k<<<MR / 4, 256, 0, stream>>>(dftb, xT, (const float2*)ptab, xfT, meanT,
                                            stdT, normT);
  transpose_norm_k<<<dim3(27, 23, 32), tb, 0, stream>>>(normT, out);

  // weight conversion into freed normT region
  conv_w_k<<<64, 256, 0, stream>>>(Wf1, 720, 64, 768, wf1h, wf1l);
  conv_w_k<<<128, 256, 0, stream>>>(Wf2, 784, 128, 832, wf2h, wf2l);
  conv_w_k<<<768, 256, 0, stream>>>(Wf3, 128, 720, 128, wf3h, wf3l);
  conv_w_k<<<256, 256, 0, stream>>>(Wp1, 720, 256, 768, wp1h, wp1l);
  conv_w_k<<<512, 256, 0, stream>>>(Wp2, 976, 512, 1024, wp2h, wp2l);
  conv_w_k<<<768, 256, 0, stream>>>(Wp3, 512, 720, 512, wp3h, wp3l);

  // freq chain
  mfma_gemm_k<0, true><<<dim3(216, 1), 256, 0, stream>>>(
      xfT, SS, SS, nullptr, 0, 12, wf1h, wf1l, 768, bf1, 64, h1, 64, 0);
  mfma_gemm_k<0, true><<<dim3(216, 2), 256, 0, stream>>>(
      h1, 64, 64, xT, SS, 13, wf2h, wf2l, 832, bf2, 128, h2, 128, 0);
  mfma_gemm_k<1, false><<<dim3(216, 12), 256, 0, stream>>>(
      h2, 128, 128, nullptr, 0, 2, wf3h, wf3l, 128, bf3, 720, out, 0, EE);

  // mean chain
  mfma_gemm_k<0, true><<<dim3(216, 4), 256, 0, stream>>>(
      meanT, SS, SS, nullptr, 0, 12, wp1h, wp1l, 768, bp1, 256, hp, 256, 0);
  mfma_gemm_k<0, true><<<dim3(216, 8), 256, 0, stream>>>(
      hp, 256, 256, xT, SS, 16, wp2h, wp2l, 1024, bp2, 512, hp2, 512, 0);
  mfma_gemm_k<1, false><<<dim3(216, 12), 256, 0, stream>>>(
      hp2, 512, 512, nullptr, 0, 8, wp3h, wp3l, 512, bp3, 720, out, 0, 2 * EE);

  // std chain
  mfma_gemm_k<0, true><<<dim3(216, 4), 256, 0, stream>>>(
      stdT, SS, SS, nullptr, 0, 12, wp1h, wp1l, 768, bp1, 256, hp, 256, 0);
  mfma_gemm_k<0, true><<<dim3(216, 8), 256, 0, stream>>>(
      hp, 256, 256, xT, SS, 16, wp2h, wp2l, 1024, bp2, 512, hp2, 512, 0);
  mfma_gemm_k<1, false><<<dim3(216, 12), 256, 0, stream>>>(
      hp2, 512, 512, nullptr, 0, 8, wp3h, wp3l, 512, bp3, 720, out, 0, 3 * EE);
}

// Round 3
// 1926.175 us; speedup vs baseline: 1.6833x; 1.1093x over previous
//
#include <hip/hip_runtime.h>

using short8 = __attribute__((ext_vector_type(8))) short;
using f32x4v = __attribute__((ext_vector_type(4))) float;

constexpr int SS = 720;
constexpr int EE = 862;
constexpr int FF = 361;           // S/2+1
constexpr int MR = 27584;         // 32*862 = 215.5*128
constexpr int NDFT = 724;         // 2*F padded to /4
constexpr int OUTSTRIDE = 4 * EE; // 3448
constexpr double PI2 = 6.283185307179586476925286766559;

__device__ __forceinline__ unsigned short f2bf(float v) {
  unsigned u = __float_as_uint(v);
  u += 0x7fff + ((u >> 16) & 1);  // RNE
  return (unsigned short)(u >> 16);
}
__device__ __forceinline__ float bf2f(unsigned short h) {
  return __uint_as_float(((unsigned)h) << 16);
}

// ---------------------------------------------------------------------------
// trig tables: W[t][f] = cos / -sin DFT matrix (720x724), ptab[t] = (cos,sin)
// ---------------------------------------------------------------------------
__global__ __launch_bounds__(256) void build_trig_k(float* __restrict__ W,
                                                    float2* __restrict__ ptab) {
  int t = blockIdx.x;
  int tid = threadIdx.x;
  for (int f = tid; f < NDFT; f += 256) {
    double v = 0.0;
    if (f < FF) {
      int idx = (int)(((long long)f * t) % SS);
      v = cos(PI2 * idx / (double)SS);
    } else if (f < 2 * FF) {
      int ff = f - FF;
      int idx = (int)(((long long)ff * t) % SS);
      v = -sin(PI2 * idx / (double)SS);
    }
    W[(size_t)t * NDFT + f] = (float)v;
  }
  if (tid == 0) {
    double ang = PI2 * t / (double)SS;
    ptab[t] = make_float2((float)cos(ang), (float)sin(ang));
  }
}

// ---------------------------------------------------------------------------
// Transpose batch_x [B,S,E] -> xT bf16 hi/lo planes [B*E][720]
// ---------------------------------------------------------------------------
__global__ __launch_bounds__(256) void transpose_in_k(const float* __restrict__ x,
                                                      unsigned short* __restrict__ xTh,
                                                      unsigned short* __restrict__ xTl) {
  __shared__ float tile[32][33];
  int b = blockIdx.z;
  int s0 = blockIdx.x * 32;
  int e0 = blockIdx.y * 32;
  int tx = threadIdx.x, ty = threadIdx.y;
#pragma unroll
  for (int j = 0; j < 4; ++j) {
    int s = s0 + ty + j * 8;
    int e = e0 + tx;
    if (s < SS && e < EE) tile[ty + j * 8][tx] = x[((size_t)b * SS + s) * EE + e];
  }
  __syncthreads();
#pragma unroll
  for (int j = 0; j < 4; ++j) {
    int e = e0 + ty + j * 8;
    int s = s0 + tx;
    if (e < EE && s < SS) {
      float v = tile[tx][ty + j * 8];
      unsigned short h = f2bf(v);
      size_t off = (size_t)(b * EE + e) * SS + s;
      xTh[off] = h;
      xTl[off] = f2bf(v - bf2f(h));
    }
  }
}

// ---------------------------------------------------------------------------
// Transpose normT [B*E, S] -> out[b,s,e] col block 0
// ---------------------------------------------------------------------------
__global__ __launch_bounds__(256) void transpose_norm_k(const float* __restrict__ normT,
                                                        float* __restrict__ out) {
  __shared__ float tile[32][33];
  int b = blockIdx.z;
  int e0 = blockIdx.x * 32;
  int s0 = blockIdx.y * 32;
  int tx = threadIdx.x, ty = threadIdx.y;
#pragma unroll
  for (int j = 0; j < 4; ++j) {
    int e = e0 + ty + j * 8;
    int s = s0 + tx;
    if (e < EE && s < SS) tile[ty + j * 8][tx] = normT[((size_t)b * EE + e) * SS + s];
  }
  __syncthreads();
#pragma unroll
  for (int j = 0; j < 4; ++j) {
    int s = s0 + ty + j * 8;
    int e = e0 + tx;
    if (s < SS && e < EE) out[((size_t)b * SS + s) * OUTSTRIDE + e] = tile[tx][ty + j * 8];
  }
}

// ---------------------------------------------------------------------------
// fp32 DFT GEMM (precision-critical path for top-k selection).
// Reads x [B,S,E] directly (A[row=(b,e)][t] = x[b][t][e]); 128x128 tile,
// 8x8 microtile as 2x2 blocks of 4x4. Grid (6, 216): col-block fastest -> L2
// reuse of the A slab across the 6 column blocks.
// ---------------------------------------------------------------------------
__global__ __launch_bounds__(256) void dft_gemm_k(const float* __restrict__ x,
                                                  const float* __restrict__ W,
                                                  float* __restrict__ C) {
  __shared__ float As[16][132];
  __shared__ float Bs[16][132];
  const int tid = threadIdx.x;
  const int n0 = blockIdx.x * 128;
  const int row0 = blockIdx.y * 128;
  const int tx = tid & 15, ty = tid >> 4;
  // A staging: thread covers (rw = tid&127, kc = (tid>>7) + 2p)
  const int rw = tid & 127;
  const int kcA = tid >> 7;
  int rowA = row0 + rw;
  if (rowA > MR - 1) rowA = MR - 1;
  const int bA = rowA / EE, eA = rowA - bA * EE;
  const float* xbase = x + (size_t)bA * (SS * EE) + eA;
  // B staging: (nn = (tid&31)*4, kk = (tid>>5) + 8p)
  const int nn = (tid & 31) * 4;
  const int kkB = tid >> 5;

  float acc[2][2][4][4] = {};

  for (int k0 = 0; k0 < SS; k0 += 16) {
    __syncthreads();
#pragma unroll
    for (int p = 0; p < 8; ++p) {
      int kc = kcA + p * 2;
      As[kc][rw] = xbase[(size_t)(k0 + kc) * EE];
    }
#pragma unroll
    for (int p = 0; p < 2; ++p) {
      int kk = kkB + p * 8;
      float4 bv = make_float4(0.f, 0.f, 0.f, 0.f);
      if (n0 + nn <= 720) bv = *(const float4*)(W + (size_t)(k0 + kk) * NDFT + n0 + nn);
      *(float4*)&Bs[kk][nn] = bv;
    }
    __syncthreads();
#pragma unroll
    for (int kk = 0; kk < 16; ++kk) {
      float a[2][4], b[2][4];
      *(float4*)a[0] = *(const float4*)&As[kk][ty * 4];
      *(float4*)a[1] = *(const float4*)&As[kk][64 + ty * 4];
      *(float4*)b[0] = *(const float4*)&Bs[kk][tx * 4];
      *(float4*)b[1] = *(const float4*)&Bs[kk][64 + tx * 4];
#pragma unroll
      for (int rg = 0; rg < 2; ++rg)
#pragma unroll
        for (int cg = 0; cg < 2; ++cg)
#pragma unroll
          for (int i = 0; i < 4; ++i)
#pragma unroll
            for (int j = 0; j < 4; ++j)
              acc[rg][cg][i][j] = fmaf(a[rg][i], b[cg][j], acc[rg][cg][i][j]);
    }
  }

#pragma unroll
  for (int rg = 0; rg < 2; ++rg)
#pragma unroll
    for (int i = 0; i < 4; ++i) {
      int r = row0 + rg * 64 + ty * 4 + i;
      if (r < MR) {
#pragma unroll
        for (int cg = 0; cg < 2; ++cg) {
          int c = n0 + cg * 64 + tx * 4;
          if (c <= 720) *(float4*)(C + (size_t)r * NDFT + c) = *(float4*)&acc[rg][cg][i][0];
        }
      }
    }
}

// ---------------------------------------------------------------------------
// Weight convert: W[K,N] fp32 -> WT hi/lo bf16 [Npad, Kp] (zero-padded)
// ---------------------------------------------------------------------------
__global__ __launch_bounds__(256) void conv_w_k(const float* __restrict__ W, int K, int N,
                                                int Kp, unsigned short* __restrict__ WTh,
                                                unsigned short* __restrict__ WTl) {
  int n = blockIdx.x;
  for (int k = threadIdx.x; k < Kp; k += 256) {
    float v = (n < N && k < K) ? W[(size_t)k * N + n] : 0.f;
    unsigned short h = f2bf(v);
    WTh[(size_t)n * Kp + k] = h;
    WTl[(size_t)n * Kp + k] = f2bf(v - bf2f(h));
  }
}

// ---------------------------------------------------------------------------
// bf16x3 MFMA GEMM, pre-split planar operands. C = [A1|A2] * W (+bias)(+relu)
// A planes row-major (strides multiple of 8); staging = short8 load +
// XOR-swizzled ds_write (no conversion VALU). BM=128 BN=64 BK=64.
// OUTMODE 0: write bf16 hi/lo planes Ch/Cl. OUTMODE 1: fp32 transposed
// scatter into d_out (LDS-staged, coalesced along e).
// ---------------------------------------------------------------------------
template <int OUTMODE, bool RELU>
__global__ __launch_bounds__(256, 2) void mfma_gemm_k(
    const unsigned short* __restrict__ A1h, const unsigned short* __restrict__ A1l,
    int sA1, int K1,
    const unsigned short* __restrict__ A2h, const unsigned short* __restrict__ A2l,
    int ktiles,
    const unsigned short* __restrict__ WTh, const unsigned short* __restrict__ WTl,
    int Kp, const float* __restrict__ bias, int N,
    unsigned short* __restrict__ Ch, unsigned short* __restrict__ Cl, int ldc,
    float* __restrict__ outF, int coloff) {
  __shared__ __align__(16) short smem[24576];
  const int tid = threadIdx.x;
  const int wid = tid >> 6, l = tid & 63;
  const int row0 = blockIdx.x * 128;
  const int n0 = blockIdx.y * 64;
  const int lg = l >> 4, lm = l & 15;

  f32x4v acc[2][4];
  const f32x4v zero4 = {0.f, 0.f, 0.f, 0.f};
#pragma unroll
  for (int i = 0; i < 2; ++i)
#pragma unroll
    for (int j = 0; j < 4; ++j) acc[i][j] = zero4;

  const short8 zero8 = {0, 0, 0, 0, 0, 0, 0, 0};

  for (int kt = 0; kt < ktiles; ++kt) {
    const int k0 = kt * 64;
    const unsigned short *srcH, *srcL;
    int str, soff, lim;
    if (k0 < K1) { srcH = A1h; srcL = A1l; str = sA1; soff = k0; lim = K1; }
    else         { srcH = A2h; srcL = A2l; str = SS;  soff = k0 - K1; lim = SS; }
    __syncthreads();
    // ---- stage A (hi & lo planes) ----
#pragma unroll
    for (int p = 0; p < 4; ++p) {
      int gid = p * 256 + tid;  // 1024 granules: 128 rows x 8
      int rw = gid >> 3, c8 = gid & 7;
      int rowg = row0 + rw;
      if (rowg > MR - 1) rowg = MR - 1;
      int col0 = soff + c8 * 8;
      short8 vh = zero8, vl = zero8;
      if (col0 < lim) {
        size_t off = (size_t)rowg * str + col0;
        vh = *(const short8*)(srcH + off);
        vl = *(const short8*)(srcL + off);
      }
      int slot = rw * 64 + ((c8 ^ (rw & 7)) << 3);
      *(short8*)&smem[slot] = vh;
      *(short8*)&smem[8192 + slot] = vl;
    }
    // ---- stage B (pre-split weights) ----
#pragma unroll
    for (int p = 0; p < 2; ++p) {
      int gid = p * 256 + tid;  // 512 granules: 64 rows x 8
      int rw = gid >> 3, c8 = gid & 7;
      size_t off = (size_t)(n0 + rw) * Kp + k0 + c8 * 8;
      short8 vh = *(const short8*)(WTh + off);
      short8 vl = *(const short8*)(WTl + off);
      int slot = rw * 64 + ((c8 ^ (rw & 7)) << 3);
      *(short8*)&smem[16384 + slot] = vh;
      *(short8*)&smem[20480 + slot] = vl;
    }
    __syncthreads();
    // ---- compute ----
#pragma unroll
    for (int ks = 0; ks < 2; ++ks) {
      short8 ah[2], al[2], bh[4], bl[4];
#pragma unroll
      for (int fi = 0; fi < 2; ++fi) {
        int r = wid * 32 + fi * 16 + lm;
        int slot = r * 64 + (((4 * ks + lg) ^ (r & 7)) << 3);
        ah[fi] = *(const short8*)&smem[slot];
        al[fi] = *(const short8*)&smem[8192 + slot];
      }
#pragma unroll
      for (int fj = 0; fj < 4; ++fj) {
        int r = fj * 16 + lm;
        int slot = r * 64 + (((4 * ks + lg) ^ (r & 7)) << 3);
        bh[fj] = *(const short8*)&smem[16384 + slot];
        bl[fj] = *(const short8*)&smem[20480 + slot];
      }
#pragma unroll
      for (int fi = 0; fi < 2; ++fi)
#pragma unroll
        for (int fj = 0; fj < 4; ++fj) {
          acc[fi][fj] = __builtin_amdgcn_mfma_f32_16x16x32_bf16(ah[fi], bh[fj], acc[fi][fj], 0, 0, 0);
          acc[fi][fj] = __builtin_amdgcn_mfma_f32_16x16x32_bf16(ah[fi], bl[fj], acc[fi][fj], 0, 0, 0);
          acc[fi][fj] = __builtin_amdgcn_mfma_f32_16x16x32_bf16(al[fi], bh[fj], acc[fi][fj], 0, 0, 0);
        }
    }
  }

  if constexpr (OUTMODE == 0) {
#pragma unroll
    for (int fi = 0; fi < 2; ++fi)
#pragma unroll
      for (int fj = 0; fj < 4; ++fj) {
        int col = n0 + fj * 16 + lm;
        float bval = bias[col];
#pragma unroll
        for (int q = 0; q < 4; ++q) {
          int row = row0 + wid * 32 + fi * 16 + lg * 4 + q;
          if (row < MR) {
            float v = acc[fi][fj][q] + bval;
            if (RELU) v = fmaxf(v, 0.f);
            unsigned short h = f2bf(v);
            Ch[(size_t)row * ldc + col] = h;
            Cl[(size_t)row * ldc + col] = f2bf(v - bf2f(h));
          }
        }
      }
  } else {
    __syncthreads();
    float* Ct = (float*)smem;  // [64 cols][132 rows]
#pragma unroll
    for (int fi = 0; fi < 2; ++fi)
#pragma unroll
      for (int fj = 0; fj < 4; ++fj) {
        int cl = fj * 16 + lm;
        int coln = n0 + cl;
        float bval = (coln < N) ? bias[coln] : 0.f;
#pragma unroll
        for (int q = 0; q < 4; ++q) {
          int rl = wid * 32 + fi * 16 + lg * 4 + q;
          Ct[cl * 132 + rl] = acc[fi][fj][q] + bval;
        }
      }
    __syncthreads();
#pragma unroll
    for (int it = 0; it < 32; ++it) {
      int idx = it * 256 + tid;
      int e_l = idx & 127, n_l = idx >> 7;
      int row = row0 + e_l, n = n0 + n_l;
      if (row < MR && n < N) {
        int b = row / EE, e = row - b * EE;
        outF[((size_t)b * SS + n) * OUTSTRIDE + coloff + e] = Ct[n_l * 132 + e_l];
      }
    }
  }
}

// ---------------------------------------------------------------------------
// helper: split 12 floats to hi/lo planes (8B-aligned ushort4 stores)
// ---------------------------------------------------------------------------
__device__ __forceinline__ void store_pair12(unsigned short* __restrict__ ph,
                                             unsigned short* __restrict__ pl,
                                             const float* v) {
#pragma unroll
  for (int g = 0; g < 3; ++g) {
    ushort4 hh, ll;
    unsigned short h;
    h = f2bf(v[g * 4 + 0]); hh.x = h; ll.x = f2bf(v[g * 4 + 0] - bf2f(h));
    h = f2bf(v[g * 4 + 1]); hh.y = h; ll.y = f2bf(v[g * 4 + 1] - bf2f(h));
    h = f2bf(v[g * 4 + 2]); hh.z = h; ll.z = f2bf(v[g * 4 + 2] - bf2f(h));
    h = f2bf(v[g * 4 + 3]); hh.w = h; ll.w = f2bf(v[g * 4 + 3] - bf2f(h));
    *(ushort4*)(ph + g * 4) = hh;
    *(ushort4*)(pl + g * 4) = ll;
  }
}

// ---------------------------------------------------------------------------
// Wave-per-row: top-20 of |X|^2 (fp32-exact), synthesize x_filtered via
// rotation recurrence, sliding window mean/std, norm. Emits bf16 hi/lo planes
// for xf/mean/std and fp32 normT.
// ---------------------------------------------------------------------------
__global__ __launch_bounds__(256) void synth_stats_k(
    const float* __restrict__ dft, const unsigned short* __restrict__ xTh,
    const unsigned short* __restrict__ xTl, const float2* __restrict__ ptab,
    unsigned short* __restrict__ xfh, unsigned short* __restrict__ xfl,
    unsigned short* __restrict__ mh, unsigned short* __restrict__ ml,
    unsigned short* __restrict__ sh, unsigned short* __restrict__ sl,
    float* __restrict__ normT) {
  __shared__ float cosT[SS], sinT[SS];
  __shared__ float nrowS[4][SS];
  __shared__ int selS[4][20];
  __shared__ float creS[4][20], cimS[4][20];

  const int tid = threadIdx.x;
  const int wid = tid >> 6, l = tid & 63;
  const int row = blockIdx.x * 4 + wid;

  for (int i = tid; i < SS; i += 256) {
    float2 p = ptab[i];
    cosT[i] = p.x;
    sinT[i] = p.y;
  }

  const float* dr = dft + (size_t)row * NDFT;
  float re[6], im[6], mg[6];
#pragma unroll
  for (int s = 0; s < 6; ++s) {
    int f = l + 64 * s;
    if (f < FF) {
      re[s] = dr[f];
      im[s] = dr[FF + f];
      mg[s] = re[s] * re[s] + im[s] * im[s];
    } else {
      re[s] = 0.f; im[s] = 0.f; mg[s] = -1e30f;
    }
  }
  __syncthreads();

  // ---- top-20 ----
  for (int k = 0; k < 20; ++k) {
    float bv = -1e29f;
    int bi = 1 << 30;
#pragma unroll
    for (int s = 0; s < 6; ++s) {
      int f = l + 64 * s;
      if (mg[s] > bv) { bv = mg[s]; bi = f; }
    }
#pragma unroll
    for (int off = 32; off >= 1; off >>= 1) {
      float ov = __shfl_xor(bv, off);
      int oi = __shfl_xor(bi, off);
      if (ov > bv || (ov == bv && oi < bi)) { bv = ov; bi = oi; }
    }
    float rw = 0.f, iw = 0.f;
    int lw = bi & 63;
    if (lw == l) {
      int sw = bi >> 6;
#pragma unroll
      for (int s = 0; s < 6; ++s)
        if (s == sw) { rw = re[s]; iw = im[s]; mg[s] = -2e30f; }
    }
    rw = __shfl(rw, lw);
    iw = __shfl(iw, lw);
    if (l == 0) {
      float cf = (bi == 0 || bi == 360) ? (1.f / 720.f) : (2.f / 720.f);
      selS[wid][k] = bi;
      creS[wid][k] = cf * rw;
      cimS[wid][k] = cf * iw;
    }
  }
  __syncthreads();

  // ---- synthesize xf for lane's 12 contiguous t (t0 = 12*l) ----
  const int t0 = 12 * l;
  float xfv[12];
#pragma unroll
  for (int j = 0; j < 12; ++j) xfv[j] = 0.f;
  for (int k = 0; k < 20; ++k) {
    int f = selS[wid][k];
    float cre = creS[wid][k], cim = cimS[wid][k];
    int i0 = (f * t0) % SS;
    float c = cosT[i0], s = sinT[i0];
    float cr = cosT[f], sr = sinT[f];
#pragma unroll
    for (int j = 0; j < 12; ++j) {
      xfv[j] = fmaf(cre, c, xfv[j]);
      xfv[j] = fmaf(-cim, s, xfv[j]);
      float cn = c * cr - s * sr;
      s = s * cr + c * sr;
      c = cn;
    }
  }

  float nr[12];
  if (l < 60) {
    const unsigned short* xhp = xTh + (size_t)row * SS + t0;
    const unsigned short* xlp = xTl + (size_t)row * SS + t0;
    float xv[12];
#pragma unroll
    for (int g = 0; g < 3; ++g) {
      ushort4 h4 = *(const ushort4*)(xhp + g * 4);
      ushort4 l4 = *(const ushort4*)(xlp + g * 4);
      xv[g * 4 + 0] = bf2f(h4.x) + bf2f(l4.x);
      xv[g * 4 + 1] = bf2f(h4.y) + bf2f(l4.y);
      xv[g * 4 + 2] = bf2f(h4.z) + bf2f(l4.z);
      xv[g * 4 + 3] = bf2f(h4.w) + bf2f(l4.w);
    }
#pragma unroll
    for (int j = 0; j < 12; ++j) nr[j] = xv[j] - xfv[j];
    store_pair12(xfh + (size_t)row * SS + t0, xfl + (size_t)row * SS + t0, xfv);
    float* np = &nrowS[wid][t0];
    *(float4*)(np + 0) = make_float4(nr[0], nr[1], nr[2], nr[3]);
    *(float4*)(np + 4) = make_float4(nr[4], nr[5], nr[6], nr[7]);
    *(float4*)(np + 8) = make_float4(nr[8], nr[9], nr[10], nr[11]);
  }
  __syncthreads();

  // ---- sliding-window stats (w=24, replicate pad) + norm ----
  if (l < 60) {
    float s1 = 0.f, s2 = 0.f;
#pragma unroll
    for (int d = -12; d < 12; ++d) {
      int u = t0 + d;
      u = u < 0 ? 0 : u;
      float v = nrowS[wid][u];
      s1 += v;
      s2 = fmaf(v, v, s2);
    }
    float mv[12], sv[12], nv[12];
#pragma unroll
    for (int j = 0; j < 12; ++j) {
      int t = t0 + j;
      float mean = s1 * (1.f / 24.f);
      float var = fmaxf(s2 * (1.f / 24.f) - mean * mean, 0.f);
      float sd = sqrtf(var + 1e-5f);
      mv[j] = mean;
      sv[j] = sd;
      nv[j] = (nr[j] - mean) / sd;
      int ua = t + 12; if (ua > SS - 1) ua = SS - 1;
      int ur = t - 12; if (ur < 0) ur = 0;
      float va = nrowS[wid][ua], vr = nrowS[wid][ur];
      s1 += va - vr;
      s2 += va * va - vr * vr;
    }
    store_pair12(mh + (size_t)row * SS + t0, ml + (size_t)row * SS + t0, mv);
    store_pair12(sh + (size_t)row * SS + t0, sl + (size_t)row * SS + t0, sv);
    float* op = normT + (size_t)row * SS + t0;
    *(float4*)(op + 0) = make_float4(nv[0], nv[1], nv[2], nv[3]);
    *(float4*)(op + 4) = make_float4(nv[4], nv[5], nv[6], nv[7]);
    *(float4*)(op + 8) = make_float4(nv[8], nv[9], nv[10], nv[11]);
  }
}

// ---------------------------------------------------------------------------
extern "C" void kernel_launch(void* const* d_in, const int* in_sizes, int n_in,
                              void* d_out, int out_size, void* d_ws, size_t ws_size,
                              hipStream_t stream) {
  const float* x = (const float*)d_in[0];
  const float* Wf1 = (const float*)d_in[1];
  const float* bf1 = (const float*)d_in[2];
  const float* Wf2 = (const float*)d_in[3];
  const float* bf2 = (const float*)d_in[4];
  const float* Wf3 = (const float*)d_in[5];
  const float* bf3 = (const float*)d_in[6];
  const float* Wp1 = (const float*)d_in[7];
  const float* bp1 = (const float*)d_in[8];
  const float* Wp2 = (const float*)d_in[9];
  const float* bp2 = (const float*)d_in[10];
  const float* Wp3 = (const float*)d_in[11];
  const float* bp3 = (const float*)d_in[12];
  float* out = (float*)d_out;
  float* ws = (float*)d_ws;

  // ---- workspace layout (floats); total 119,795,936 <= proven 121,009,632 ----
  constexpr size_t PSF = (size_t)MR * SS / 2;  // one bf16 plane = 9,930,240 floats
  unsigned short* xTh = (unsigned short*)(ws + 0 * PSF);
  unsigned short* xTl = (unsigned short*)(ws + 1 * PSF);
  unsigned short* xfh = (unsigned short*)(ws + 2 * PSF);
  unsigned short* xfl = (unsigned short*)(ws + 3 * PSF);
  unsigned short* mh  = (unsigned short*)(ws + 4 * PSF);
  unsigned short* ml  = (unsigned short*)(ws + 5 * PSF);
  unsigned short* sh  = (unsigned short*)(ws + 6 * PSF);
  unsigned short* sl  = (unsigned short*)(ws + 7 * PSF);
  float* dft = ws + 8 * PSF;                       // MR*724 = 19,970,816 floats
  float* normT = dft + (size_t)MR * NDFT;          // 19,860,480 floats
  float* trig = normT + (size_t)MR * SS;           // 521,280 floats
  float* ptab = trig + (size_t)SS * NDFT;          // 1,440 floats

  // overlay 1: dft region (dead after synth) -> h1/h2/hp planes (12.36M fl)
  unsigned short* h1h = (unsigned short*)dft;
  unsigned short* h1l = h1h + (size_t)MR * 64;
  unsigned short* h2h = h1l + (size_t)MR * 64;
  unsigned short* h2l = h2h + (size_t)MR * 128;
  unsigned short* hph = h2l + (size_t)MR * 128;
  unsigned short* hpl = hph + (size_t)MR * 256;
  // overlay 2: normT region (dead after transpose_norm) -> weights + hp2 (15.49M fl)
  unsigned short* wq = (unsigned short*)normT;
  unsigned short* wf1h = wq;
  unsigned short* wf1l = wf1h + 64 * 768;
  unsigned short* wf2h = wf1l + 64 * 768;
  unsigned short* wf2l = wf2h + 128 * 832;
  unsigned short* wf3h = wf2l + 128 * 832;
  unsigned short* wf3l = wf3h + 768 * 128;
  unsigned short* wp1h = wf3l + 768 * 128;
  unsigned short* wp1l = wp1h + 256 * 768;
  unsigned short* wp2h = wp1l + 256 * 768;
  unsigned short* wp2l = wp2h + 512 * 1024;
  unsigned short* wp3h = wp2l + 512 * 1024;
  unsigned short* wp3l = wp3h + 768 * 512;
  unsigned short* hp2h = wp3l + 768 * 512;
  unsigned short* hp2l = hp2h + (size_t)MR * 512;

  dim3 tb(32, 8);

  build_trig_k<<<SS, 256, 0, stream>>>(trig, (float2*)ptab);
  transpose_in_k<<<dim3(23, 27, 32), tb, 0, stream>>>(x, xTh, xTl);
  dft_gemm_k<<<dim3(6, 216), 256, 0, stream>>>(x, trig, dft);
  synth_stats_k<<<MR / 4, 256, 0, stream>>>(dft, xTh, xTl, (const float2*)ptab,
                                            xfh, xfl, mh, ml, sh, sl, normT);
  transpose_norm_k<<<dim3(27, 23, 32), tb, 0, stream>>>(normT, out);

  // weights (overlay normT region; runs after transpose_norm)
  conv_w_k<<<64, 256, 0, stream>>>(Wf1, 720, 64, 768, wf1h, wf1l);
  conv_w_k<<<128, 256, 0, stream>>>(Wf2, 784, 128, 832, wf2h, wf2l);
  conv_w_k<<<768, 256, 0, stream>>>(Wf3, 128, 720, 128, wf3h, wf3l);
  conv_w_k<<<256, 256, 0, stream>>>(Wp1, 720, 256, 768, wp1h, wp1l);
  conv_w_k<<<512, 256, 0, stream>>>(Wp2, 976, 512, 1024, wp2h, wp2l);
  conv_w_k<<<768, 256, 0, stream>>>(Wp3, 512, 720, 512, wp3h, wp3l);

  // freq chain
  mfma_gemm_k<0, true><<<dim3(216, 1), 256, 0, stream>>>(
      xfh, xfl, SS, SS, nullptr, nullptr, 12, wf1h, wf1l, 768, bf1, 64,
      h1h, h1l, 64, nullptr, 0);
  mfma_gemm_k<0, true><<<dim3(216, 2), 256, 0, stream>>>(
      h1h, h1l, 64, 64, xTh, xTl, 13, wf2h, wf2l, 832, bf2, 128,
      h2h, h2l, 128, nullptr, 0);
  mfma_gemm_k<1, false><<<dim3(216, 12), 256, 0, stream>>>(
      h2h, h2l, 128, 128, nullptr, nullptr, 2, wf3h, wf3l, 128, bf3, 720,
      nullptr, nullptr, 0, out, EE);

  // mean chain
  mfma_gemm_k<0, true><<<dim3(216, 4), 256, 0, stream>>>(
      mh, ml, SS, SS, nullptr, nullptr, 12, wp1h, wp1l, 768, bp1, 256,
      hph, hpl, 256, nullptr, 0);
  mfma_gemm_k<0, true><<<dim3(216, 8), 256, 0, stream>>>(
      hph, hpl, 256, 256, xTh, xTl, 16, wp2h, wp2l, 1024, bp2, 512,
      hp2h, hp2l, 512, nullptr, 0);
  mfma_gemm_k<1, false><<<dim3(216, 12), 256, 0, stream>>>(
      hp2h, hp2l, 512, 512, nullptr, nullptr, 8, wp3h, wp3l, 512, bp3, 720,
      nullptr, nullptr, 0, out, 2 * EE);

  // std chain
  mfma_gemm_k<0, true><<<dim3(216, 4), 256, 0, stream>>>(
      sh, sl, SS, SS, nullptr, nullptr, 12, wp1h, wp1l, 768, bp1, 256,
      hph, hpl, 256, nullptr, 0);
  mfma_gemm_k<0, true><<<dim3(216, 8), 256, 0, stream>>>(
      hph, hpl, 256, 256, xTh, xTl, 16, wp2h, wp2l, 1024, bp2, 512,
      hp2h, hp2l, 512, nullptr, 0);
  mfma_gemm_k<1, false><<<dim3(216, 12), 256, 0, stream>>>(
      hp2h, hp2l, 512, 512, nullptr, nullptr, 8, wp3h, wp3l, 512, bp3, 720,
      nullptr, nullptr, 0, out, 3 * EE);
}